// Round 4
// baseline (69.758 us; speedup 1.0000x reference)
//
#include <hip/hip_runtime.h>
#include <hip/hip_bf16.h>

#define BATCH     32768
#define TILE      32
#define NPAIR     64
#define NBLK      128          /* route blocks: BATCH/256 */
#define MAXSCHED  1088         /* 64 + BATCH/TILE = 8*136 */

typedef __bf16 bf16x8 __attribute__((ext_vector_type(8)));
typedef float  f32x4  __attribute__((ext_vector_type(4)));
static_assert(sizeof(bf16x8) == 16, "bf16x8 must be 16B");

// ---- workspace byte offsets ----
#define WS_BH       1024
#define WS_OFF      (WS_BH + NBLK*NPAIR*4)          /* 33792 */
#define WS_SCHED    (WS_OFF + NBLK*NPAIR*4)         /* 66560, int4 per tile */
#define WS_PAIR     (WS_SCHED + MAXSCHED*16)        /* 83968 */
#define WS_ROWLIST  (WS_PAIR + BATCH*4)
#define WS_WT00     (WS_ROWLIST + BATCH*4)
#define WS_WT01     (WS_WT00 + 131072*2)
#define WS_WT1P     (WS_WT01 + 262144*2)
#define WS_WT1A     (WS_WT1P + 131072*2)
#define WS_WT1O     (WS_WT1A + 393216*2)

__device__ __forceinline__ unsigned short f2bf(float x) {
  __bf16 h = (__bf16)x;
  return __builtin_bit_cast(unsigned short, h);
}

// Merged: blocks 0..239 transpose weights fp32->bf16 [m][o][i]; blocks 240..367 route.
__global__ __launch_bounds__(256) void k_combo(const float* __restrict__ w00,
                                               const float* __restrict__ w01,
                                               const float* __restrict__ w1p,
                                               const float* __restrict__ w1a,
                                               const float* __restrict__ w1o,
                                               const float* __restrict__ inp,
                                               char* __restrict__ ws) {
  __shared__ unsigned short lds[64 * 72];
  int bid = blockIdx.x;
  if (bid >= 240) {
    // ---- route: per-block histogram, NO global atomics ----
    int* h = (int*)lds;
    int rbid = bid - 240;
    int t = threadIdx.x;
    if (t < NPAIR) h[t] = 0;
    __syncthreads();
    int r = rbid * 256 + t;
    const float* q = inp + (size_t)r * 144 + 128;
    float4 u0 = *(const float4*)(q + 0);
    float4 u1 = *(const float4*)(q + 4);
    float4 v0 = *(const float4*)(q + 8);
    float4 v1 = *(const float4*)(q + 12);
    int a0 = 0;
    if (u0.y > 0.5f) a0 = 1; if (u0.z > 0.5f) a0 = 2; if (u0.w > 0.5f) a0 = 3;
    if (u1.x > 0.5f) a0 = 4; if (u1.y > 0.5f) a0 = 5; if (u1.z > 0.5f) a0 = 6; if (u1.w > 0.5f) a0 = 7;
    int a1 = 0;
    if (v0.y > 0.5f) a1 = 1; if (v0.z > 0.5f) a1 = 2; if (v0.w > 0.5f) a1 = 3;
    if (v1.x > 0.5f) a1 = 4; if (v1.y > 0.5f) a1 = 5; if (v1.z > 0.5f) a1 = 6; if (v1.w > 0.5f) a1 = 7;
    int p = a0 * 8 + a1;
    ((int*)(ws + WS_PAIR))[r] = p;
    atomicAdd(&h[p], 1);
    __syncthreads();
    if (t < NPAIR) ((int*)(ws + WS_BH))[rbid * NPAIR + t] = h[t];
    return;
  }
  // ---- weight transpose ----
  const float* src; unsigned short* dst; int I, O, lt;
  if (bid < 32)       { src = w00; dst = (unsigned short*)(ws + WS_WT00); I = 64;  O = 256; lt = bid; }
  else if (bid < 96)  { src = w01; dst = (unsigned short*)(ws + WS_WT01); I = 256; O = 128; lt = bid - 32; }
  else if (bid < 128) { src = w1p; dst = (unsigned short*)(ws + WS_WT1P); I = 64;  O = 256; lt = bid - 96; }
  else if (bid < 224) { src = w1a; dst = (unsigned short*)(ws + WS_WT1A); I = 384; O = 128; lt = bid - 128; }
  else                { src = w1o; dst = (unsigned short*)(ws + WS_WT1O); I = 128; O = 32;  lt = bid - 224; }
  int tI = I >> 6;
  int tO = (O + 63) >> 6;
  int m   = lt / (tI * tO);
  int rem = lt % (tI * tO);
  int ib = rem / tO, ob = rem % tO;
  int tx = threadIdx.x & 63, ty = threadIdx.x >> 6;
  const float* s = src + (size_t)m * I * O;
  #pragma unroll 4
  for (int s4 = 0; s4 < 16; ++s4) {
    int li = s4 * 4 + ty;
    int o  = ob * 64 + tx;
    float v = (o < O) ? s[(size_t)(ib * 64 + li) * O + o] : 0.f;
    lds[li * 72 + tx] = f2bf(v);
  }
  __syncthreads();
  unsigned short* d = dst + (size_t)m * O * I;
  #pragma unroll 4
  for (int s4 = 0; s4 < 16; ++s4) {
    int lo = s4 * 4 + ty;
    int o  = ob * 64 + lo;
    if (o < O) d[(size_t)o * I + ib * 64 + tx] = lds[tx * 72 + lo];
  }
}

// Scan: 1 block x 1024 threads. Chunked two-level scan; packs schedule as int4{p,rb,nr,0}.
__global__ __launch_bounds__(1024) void k_scan(const int* __restrict__ bh,
                                               int* __restrict__ off,
                                               int4* __restrict__ sched) {
  __shared__ int part[16][NPAIR];
  __shared__ int bs64[NPAIR];
  int tid = threadIdx.x;
  int p = tid & 63, c = tid >> 6;       // 16 chunks x 8 blocks
  int loc[8]; int s = 0;
  #pragma unroll
  for (int i = 0; i < 8; ++i) { loc[i] = s; s += bh[(c * 8 + i) * NPAIR + p]; }
  part[c][p] = s;
  for (int j = tid; j < MAXSCHED; j += 1024) sched[j] = make_int4(0, 0, 0, 0);
  __syncthreads();
  if (tid < 64) {
    int run = 0;
    #pragma unroll
    for (int c2 = 0; c2 < 16; ++c2) { int v = part[c2][p]; part[c2][p] = run; run += v; }
    int x = run;
    #pragma unroll
    for (int d = 1; d < 64; d <<= 1) { int y = __shfl_up(x, d); if (p >= d) x += y; }
    int bs = x - run;
    bs64[p] = bs;
    int nt = (run + TILE - 1) / TILE;
    int z = nt;
    #pragma unroll
    for (int d = 1; d < 64; d <<= 1) { int y = __shfl_up(z, d); if (p >= d) z += y; }
    int tb = z - nt;
    for (int t2 = 0; t2 < nt; ++t2)
      sched[tb + t2] = make_int4(p, bs + t2 * TILE, min(TILE, run - t2 * TILE), 0);
  }
  __syncthreads();
  int add = part[c][p] + bs64[p];
  #pragma unroll
  for (int i = 0; i < 8; ++i) off[(c * 8 + i) * NPAIR + p] = loc[i] + add;
}

// Scatter: LDS-local rank + precomputed global offset. NO global atomics.
__global__ __launch_bounds__(256) void k_scatter(const int* __restrict__ pairArr,
                                                 const int* __restrict__ off,
                                                 int* __restrict__ rowlist) {
  __shared__ int h[NPAIR];
  int t = threadIdx.x;
  if (t < NPAIR) h[t] = 0;
  __syncthreads();
  int r = blockIdx.x * 256 + t;
  int p = pairArr[r];
  int rank = atomicAdd(&h[p], 1);
  rowlist[off[blockIdx.x * NPAIR + p] + rank] = r;
}

// Fused 5-layer routed MLP. One block = 32 rows sharing (a0,a1); 4 waves; 32KB LDS
// (HO aliases dead G, G2 aliases dead H1). TLP-first: 5 blocks/CU resident, whole
// grid co-resident in one round. Weights load at-use, hidden by 5 waves/SIMD.
// Swizzle: byte ^= (row&7)<<4 on all tiles.
__global__ __launch_bounds__(256, 5) void k_fused(
    const float* __restrict__ inp,
    const float* __restrict__ b00, const float* __restrict__ b01,
    const float* __restrict__ b1p, const float* __restrict__ b1a,
    const float* __restrict__ b1o,
    const char* __restrict__ ws, float* __restrict__ out)
{
  __shared__ char smem[32768];
  unsigned short* G   = (unsigned short*)smem;            // 32x256, stride 512B
  unsigned short* H1m = (unsigned short*)(smem + 16384);  // 32x256, stride 512B
  unsigned short* HO  = (unsigned short*)smem;            // 32x128, stride 256B (aliases G)
  unsigned short* G2  = (unsigned short*)(smem + 16384);  // 32x128, stride 256B (aliases H1)

  // XCD-aware remap: a pair's consecutive tiles land on one XCD's L2.
  int sid = (blockIdx.x & 7) * (MAXSCHED / 8) + (blockIdx.x >> 3);
  int4 se = ((const int4*)(ws + WS_SCHED))[sid];
  int nr = se.z;
  if (nr <= 0) return;
  int p = se.x, rb = se.y;
  int e0 = p >> 3, e1 = p & 7;
  const int* rl = (const int*)(ws + WS_ROWLIST) + rb;

  const unsigned short* wt00 = (const unsigned short*)(ws + WS_WT00);
  const unsigned short* wt01 = (const unsigned short*)(ws + WS_WT01);
  const unsigned short* wt1p = (const unsigned short*)(ws + WS_WT1P);
  const unsigned short* wt1a = (const unsigned short*)(ws + WS_WT1A);
  const unsigned short* wt1o = (const unsigned short*)(ws + WS_WT1O);

  int lane = threadIdx.x & 63;
  int w    = threadIdx.x >> 6;   // wave 0..3
  int ln   = lane & 15;
  int lq   = lane >> 4;          // 0..3
  int kcol = lq * 8;

  int rowA[2];
  #pragma unroll
  for (int mt = 0; mt < 2; ++mt) {
    int rloc = mt * 16 + ln;
    rowA[mt] = (rloc < nr) ? rl[rloc] : -1;
  }

  // Input fragments (feed both L1p and L00).
  bf16x8 axf[2][2][2];  // [half][mt][kc]
  #pragma unroll
  for (int mt = 0; mt < 2; ++mt) {
    #pragma unroll
    for (int half = 0; half < 2; ++half) {
      #pragma unroll
      for (int kc = 0; kc < 2; ++kc) {
        bf16x8 a;
        int rg = rowA[mt];
        if (rg >= 0) {
          const float* q = inp + (size_t)rg * 144 + half * 64 + kc * 32 + kcol;
          float4 u = *(const float4*)(q);
          float4 v = *(const float4*)(q + 4);
          a[0] = (__bf16)u.x; a[1] = (__bf16)u.y; a[2] = (__bf16)u.z; a[3] = (__bf16)u.w;
          a[4] = (__bf16)v.x; a[5] = (__bf16)v.y; a[6] = (__bf16)v.z; a[7] = (__bf16)v.w;
        } else {
          #pragma unroll
          for (int j = 0; j < 8; ++j) a[j] = (__bf16)0.f;
        }
        axf[half][mt][kc] = a;
      }
    }
  }

  const f32x4 z4 = {0.f, 0.f, 0.f, 0.f};

  // ===== Phase 1: L1p -> G, L00 -> H1 (relu) =====
  #pragma unroll
  for (int nt = 0; nt < 4; ++nt) {
    int n = w * 64 + nt * 16 + ln;
    f32x4 acc[2] = {z4, z4};
    #pragma unroll
    for (int kc = 0; kc < 2; ++kc) {
      bf16x8 bfr = *(const bf16x8*)(wt1p + ((size_t)(e1 * 256 + n) * 64 + kc * 32 + kcol));
      #pragma unroll
      for (int mt = 0; mt < 2; ++mt)
        acc[mt] = __builtin_amdgcn_mfma_f32_16x16x32_bf16(axf[1][mt][kc], bfr, acc[mt], 0, 0, 0);
    }
    float bias = b1p[e1 * 256 + n];
    #pragma unroll
    for (int mt = 0; mt < 2; ++mt)
      #pragma unroll
      for (int r = 0; r < 4; ++r) {
        int row = mt * 16 + lq * 4 + r;
        float v = fmaxf(acc[mt][r] + bias, 0.f);
        G[(row * 512 + ((n << 1) ^ ((row & 7) << 4))) >> 1] = f2bf(v);
      }
  }
  #pragma unroll
  for (int nt = 0; nt < 4; ++nt) {
    int n = w * 64 + nt * 16 + ln;
    f32x4 acc[2] = {z4, z4};
    #pragma unroll
    for (int kc = 0; kc < 2; ++kc) {
      bf16x8 bfr = *(const bf16x8*)(wt00 + ((size_t)(e0 * 256 + n) * 64 + kc * 32 + kcol));
      #pragma unroll
      for (int mt = 0; mt < 2; ++mt)
        acc[mt] = __builtin_amdgcn_mfma_f32_16x16x32_bf16(axf[0][mt][kc], bfr, acc[mt], 0, 0, 0);
    }
    float bias = b00[e0 * 256 + n];
    #pragma unroll
    for (int mt = 0; mt < 2; ++mt)
      #pragma unroll
      for (int r = 0; r < 4; ++r) {
        int row = mt * 16 + lq * 4 + r;
        float v = fmaxf(acc[mt][r] + bias, 0.f);
        H1m[(row * 512 + ((n << 1) ^ ((row & 7) << 4))) >> 1] = f2bf(v);
      }
  }
  __syncthreads();

  // ===== Phase 2: acc1a = W1a-g @ G ; accc = W01 @ H1 (registers only) =====
  f32x4 acc1a[2][2], accc[2][2];
  #pragma unroll
  for (int nt = 0; nt < 2; ++nt)
    #pragma unroll
    for (int mt = 0; mt < 2; ++mt) { acc1a[nt][mt] = z4; accc[nt][mt] = z4; }

  #pragma unroll
  for (int kc = 0; kc < 8; ++kc) {
    bf16x8 afr[2];
    #pragma unroll
    for (int mt = 0; mt < 2; ++mt) {
      int row = mt * 16 + ln;
      afr[mt] = *(const bf16x8*)&G[(row * 512 + (((kc * 32 + kcol) << 1) ^ ((row & 7) << 4))) >> 1];
    }
    #pragma unroll
    for (int nt = 0; nt < 2; ++nt) {
      int n = w * 32 + nt * 16 + ln;
      bf16x8 bfr = *(const bf16x8*)(wt1a + ((size_t)(e1 * 128 + n) * 384 + 128 + kc * 32 + kcol));
      #pragma unroll
      for (int mt = 0; mt < 2; ++mt)
        acc1a[nt][mt] = __builtin_amdgcn_mfma_f32_16x16x32_bf16(afr[mt], bfr, acc1a[nt][mt], 0, 0, 0);
    }
  }
  #pragma unroll
  for (int kc = 0; kc < 8; ++kc) {
    bf16x8 afr[2];
    #pragma unroll
    for (int mt = 0; mt < 2; ++mt) {
      int row = mt * 16 + ln;
      afr[mt] = *(const bf16x8*)&H1m[(row * 512 + (((kc * 32 + kcol) << 1) ^ ((row & 7) << 4))) >> 1];
    }
    #pragma unroll
    for (int nt = 0; nt < 2; ++nt) {
      int n = w * 32 + nt * 16 + ln;
      bf16x8 bfr = *(const bf16x8*)(wt01 + ((size_t)(e0 * 128 + n) * 256 + kc * 32 + kcol));
      #pragma unroll
      for (int mt = 0; mt < 2; ++mt)
        accc[nt][mt] = __builtin_amdgcn_mfma_f32_16x16x32_bf16(afr[mt], bfr, accc[nt][mt], 0, 0, 0);
    }
  }
  __syncthreads();  // all G/H1 reads done

  // ===== write HO = relu(accc + b01) over dead G =====
  #pragma unroll
  for (int nt = 0; nt < 2; ++nt) {
    int n = w * 32 + nt * 16 + ln;
    float bias = b01[e0 * 128 + n];
    #pragma unroll
    for (int mt = 0; mt < 2; ++mt)
      #pragma unroll
      for (int r = 0; r < 4; ++r) {
        int row = mt * 16 + lq * 4 + r;
        float v = fmaxf(accc[nt][mt][r] + bias, 0.f);
        HO[(row * 256 + ((n << 1) ^ ((row & 7) << 4))) >> 1] = f2bf(v);
      }
  }
  __syncthreads();

  // ===== Phase 3: acc1a += W1a-h @ HO; G2 = relu(acc1a + b1a) over dead H1 =====
  #pragma unroll
  for (int kc = 0; kc < 4; ++kc) {
    bf16x8 afr[2];
    #pragma unroll
    for (int mt = 0; mt < 2; ++mt) {
      int row = mt * 16 + ln;
      afr[mt] = *(const bf16x8*)&HO[(row * 256 + (((kc * 32 + kcol) << 1) ^ ((row & 7) << 4))) >> 1];
    }
    #pragma unroll
    for (int nt = 0; nt < 2; ++nt) {
      int n = w * 32 + nt * 16 + ln;
      bf16x8 bfr = *(const bf16x8*)(wt1a + ((size_t)(e1 * 128 + n) * 384 + kc * 32 + kcol));
      #pragma unroll
      for (int mt = 0; mt < 2; ++mt)
        acc1a[nt][mt] = __builtin_amdgcn_mfma_f32_16x16x32_bf16(afr[mt], bfr, acc1a[nt][mt], 0, 0, 0);
    }
  }
  #pragma unroll
  for (int nt = 0; nt < 2; ++nt) {
    int n = w * 32 + nt * 16 + ln;
    float bias = b1a[e1 * 128 + n];
    #pragma unroll
    for (int mt = 0; mt < 2; ++mt)
      #pragma unroll
      for (int r = 0; r < 4; ++r) {
        int row = mt * 16 + lq * 4 + r;
        float v = fmaxf(acc1a[nt][mt][r] + bias, 0.f);
        G2[(row * 256 + ((n << 1) ^ ((row & 7) << 4))) >> 1] = f2bf(v);
      }
  }
  __syncthreads();

  // ===== Phase 4: L1o: G2 @ W1o[e1] -> out (32), no relu, fp32 scatter =====
  {
    int mt = w & 1;
    int n  = (w >> 1) * 16 + ln;
    f32x4 acc = z4;
    #pragma unroll
    for (int kc = 0; kc < 4; ++kc) {
      int row = mt * 16 + ln;
      bf16x8 afr = *(const bf16x8*)&G2[(row * 256 + (((kc * 32 + kcol) << 1) ^ ((row & 7) << 4))) >> 1];
      bf16x8 bfr = *(const bf16x8*)(wt1o + ((size_t)(e1 * 32 + n) * 128 + kc * 32 + kcol));
      acc = __builtin_amdgcn_mfma_f32_16x16x32_bf16(afr, bfr, acc, 0, 0, 0);
    }
    float bias = b1o[e1 * 32 + n];
    #pragma unroll
    for (int r = 0; r < 4; ++r) {
      int row = mt * 16 + lq * 4 + r;
      if (row < nr) {
        int rg = rl[row];
        out[(size_t)rg * 32 + n] = acc[r] + bias;
      }
    }
  }
}

extern "C" void kernel_launch(void* const* d_in, const int* in_sizes, int n_in,
                              void* d_out, int out_size, void* d_ws, size_t ws_size,
                              hipStream_t stream) {
  const float* inp = (const float*)d_in[0];
  const float* w00 = (const float*)d_in[1];
  const float* b00 = (const float*)d_in[2];
  const float* w01 = (const float*)d_in[3];
  const float* b01 = (const float*)d_in[4];
  const float* w1p = (const float*)d_in[5];
  const float* b1p = (const float*)d_in[6];
  const float* w1a = (const float*)d_in[7];
  const float* b1a = (const float*)d_in[8];
  const float* w1o = (const float*)d_in[9];
  const float* b1o = (const float*)d_in[10];
  char*  ws  = (char*)d_ws;
  float* out = (float*)d_out;

  k_combo<<<368, 256, 0, stream>>>(w00, w01, w1p, w1a, w1o, inp, ws);
  k_scan<<<1, 1024, 0, stream>>>((const int*)(ws + WS_BH), (int*)(ws + WS_OFF),
                                 (int4*)(ws + WS_SCHED));
  k_scatter<<<NBLK, 256, 0, stream>>>((const int*)(ws + WS_PAIR),
                                      (const int*)(ws + WS_OFF),
                                      (int*)(ws + WS_ROWLIST));
  k_fused<<<MAXSCHED, 256, 0, stream>>>(inp, b00, b01, b1p, b1a, b1o, ws, out);
}

// Round 5
// 64.795 us; speedup vs baseline: 1.0766x; 1.0766x over previous
//
#include <hip/hip_runtime.h>
#include <hip/hip_bf16.h>

#define BATCH     32768
#define TILE      32
#define NPAIR     64
#define NBLK      128          /* route blocks: BATCH/256 */
#define MAXSCHED  1088         /* 64 + BATCH/TILE = 8*136 */

typedef __bf16 bf16x8 __attribute__((ext_vector_type(8)));
typedef float  f32x4  __attribute__((ext_vector_type(4)));
static_assert(sizeof(bf16x8) == 16, "bf16x8 must be 16B");

// ---- workspace byte offsets ----
#define WS_BH       1024
#define WS_OFF      (WS_BH + NBLK*NPAIR*4)          /* 33792 */
#define WS_SCHED    (WS_OFF + NBLK*NPAIR*4)         /* 66560, int4 per tile */
#define WS_PAIR     (WS_SCHED + MAXSCHED*16)        /* 83968 */
#define WS_ROWLIST  (WS_PAIR + BATCH*4)
#define WS_WT00     (WS_ROWLIST + BATCH*4)
#define WS_WT01     (WS_WT00 + 131072*2)
#define WS_WT1P     (WS_WT01 + 262144*2)
#define WS_WT1A     (WS_WT1P + 131072*2)
#define WS_WT1O     (WS_WT1A + 393216*2)

__device__ __forceinline__ unsigned short f2bf(float x) {
  __bf16 h = (__bf16)x;
  return __builtin_bit_cast(unsigned short, h);
}

// Single-asm batch pins: all listed values must be materialized at this point.
// One asm per batch => the loads issue as a batch and cost ONE latency.
#define PIN16(A) asm volatile("" :: \
  "v"((A)[0]),"v"((A)[1]),"v"((A)[2]),"v"((A)[3]),"v"((A)[4]),"v"((A)[5]),"v"((A)[6]),"v"((A)[7]), \
  "v"((A)[8]),"v"((A)[9]),"v"((A)[10]),"v"((A)[11]),"v"((A)[12]),"v"((A)[13]),"v"((A)[14]),"v"((A)[15]))
#define PIN12(A) asm volatile("" :: \
  "v"((A)[0]),"v"((A)[1]),"v"((A)[2]),"v"((A)[3]),"v"((A)[4]),"v"((A)[5]),"v"((A)[6]),"v"((A)[7]), \
  "v"((A)[8]),"v"((A)[9]),"v"((A)[10]),"v"((A)[11]))

// Merged: blocks 0..239 transpose weights fp32->bf16 [m][o][i]; blocks 240..367 route.
__global__ __launch_bounds__(256) void k_combo(const float* __restrict__ w00,
                                               const float* __restrict__ w01,
                                               const float* __restrict__ w1p,
                                               const float* __restrict__ w1a,
                                               const float* __restrict__ w1o,
                                               const float* __restrict__ inp,
                                               char* __restrict__ ws) {
  __shared__ unsigned short lds[64 * 72];
  int bid = blockIdx.x;
  if (bid >= 240) {
    int* h = (int*)lds;
    int rbid = bid - 240;
    int t = threadIdx.x;
    if (t < NPAIR) h[t] = 0;
    __syncthreads();
    int r = rbid * 256 + t;
    const float* q = inp + (size_t)r * 144 + 128;
    float4 u0 = *(const float4*)(q + 0);
    float4 u1 = *(const float4*)(q + 4);
    float4 v0 = *(const float4*)(q + 8);
    float4 v1 = *(const float4*)(q + 12);
    int a0 = 0;
    if (u0.y > 0.5f) a0 = 1; if (u0.z > 0.5f) a0 = 2; if (u0.w > 0.5f) a0 = 3;
    if (u1.x > 0.5f) a0 = 4; if (u1.y > 0.5f) a0 = 5; if (u1.z > 0.5f) a0 = 6; if (u1.w > 0.5f) a0 = 7;
    int a1 = 0;
    if (v0.y > 0.5f) a1 = 1; if (v0.z > 0.5f) a1 = 2; if (v0.w > 0.5f) a1 = 3;
    if (v1.x > 0.5f) a1 = 4; if (v1.y > 0.5f) a1 = 5; if (v1.z > 0.5f) a1 = 6; if (v1.w > 0.5f) a1 = 7;
    int p = a0 * 8 + a1;
    ((int*)(ws + WS_PAIR))[r] = p;
    atomicAdd(&h[p], 1);
    __syncthreads();
    if (t < NPAIR) ((int*)(ws + WS_BH))[rbid * NPAIR + t] = h[t];
    return;
  }
  const float* src; unsigned short* dst; int I, O, lt;
  if (bid < 32)       { src = w00; dst = (unsigned short*)(ws + WS_WT00); I = 64;  O = 256; lt = bid; }
  else if (bid < 96)  { src = w01; dst = (unsigned short*)(ws + WS_WT01); I = 256; O = 128; lt = bid - 32; }
  else if (bid < 128) { src = w1p; dst = (unsigned short*)(ws + WS_WT1P); I = 64;  O = 256; lt = bid - 96; }
  else if (bid < 224) { src = w1a; dst = (unsigned short*)(ws + WS_WT1A); I = 384; O = 128; lt = bid - 128; }
  else                { src = w1o; dst = (unsigned short*)(ws + WS_WT1O); I = 128; O = 32;  lt = bid - 224; }
  int tI = I >> 6;
  int tO = (O + 63) >> 6;
  int m   = lt / (tI * tO);
  int rem = lt % (tI * tO);
  int ib = rem / tO, ob = rem % tO;
  int tx = threadIdx.x & 63, ty = threadIdx.x >> 6;
  const float* s = src + (size_t)m * I * O;
  #pragma unroll 4
  for (int s4 = 0; s4 < 16; ++s4) {
    int li = s4 * 4 + ty;
    int o  = ob * 64 + tx;
    float v = (o < O) ? s[(size_t)(ib * 64 + li) * O + o] : 0.f;
    lds[li * 72 + tx] = f2bf(v);
  }
  __syncthreads();
  unsigned short* d = dst + (size_t)m * O * I;
  #pragma unroll 4
  for (int s4 = 0; s4 < 16; ++s4) {
    int lo = s4 * 4 + ty;
    int o  = ob * 64 + lo;
    if (o < O) d[(size_t)o * I + ib * 64 + tx] = lds[tx * 72 + lo];
  }
}

// Scan: 1 block x 1024 threads. Chunked two-level scan; packs schedule as int4{p,rb,nr,0}.
__global__ __launch_bounds__(1024) void k_scan(const int* __restrict__ bh,
                                               int* __restrict__ off,
                                               int4* __restrict__ sched) {
  __shared__ int part[16][NPAIR];
  __shared__ int bs64[NPAIR];
  int tid = threadIdx.x;
  int p = tid & 63, c = tid >> 6;
  int loc[8]; int s = 0;
  #pragma unroll
  for (int i = 0; i < 8; ++i) { loc[i] = s; s += bh[(c * 8 + i) * NPAIR + p]; }
  part[c][p] = s;
  for (int j = tid; j < MAXSCHED; j += 1024) sched[j] = make_int4(0, 0, 0, 0);
  __syncthreads();
  if (tid < 64) {
    int run = 0;
    #pragma unroll
    for (int c2 = 0; c2 < 16; ++c2) { int v = part[c2][p]; part[c2][p] = run; run += v; }
    int x = run;
    #pragma unroll
    for (int d = 1; d < 64; d <<= 1) { int y = __shfl_up(x, d); if (p >= d) x += y; }
    int bs = x - run;
    bs64[p] = bs;
    int nt = (run + TILE - 1) / TILE;
    int z = nt;
    #pragma unroll
    for (int d = 1; d < 64; d <<= 1) { int y = __shfl_up(z, d); if (p >= d) z += y; }
    int tb = z - nt;
    for (int t2 = 0; t2 < nt; ++t2)
      sched[tb + t2] = make_int4(p, bs + t2 * TILE, min(TILE, run - t2 * TILE), 0);
  }
  __syncthreads();
  int add = part[c][p] + bs64[p];
  #pragma unroll
  for (int i = 0; i < 8; ++i) off[(c * 8 + i) * NPAIR + p] = loc[i] + add;
}

// Scatter: LDS-local rank + precomputed global offset. NO global atomics.
__global__ __launch_bounds__(256) void k_scatter(const int* __restrict__ pairArr,
                                                 const int* __restrict__ off,
                                                 int* __restrict__ rowlist) {
  __shared__ int h[NPAIR];
  int t = threadIdx.x;
  if (t < NPAIR) h[t] = 0;
  __syncthreads();
  int r = blockIdx.x * 256 + threadIdx.x;
  int p = pairArr[r];
  int rank = atomicAdd(&h[p], 1);
  rowlist[off[blockIdx.x * NPAIR + p] + rank] = r;
}

// Fused 5-layer routed MLP. Block = 32 rows of one (a0,a1) pair; 4 waves; 48KB LDS
// (no aliasing): G@0 H1@16K HO@32K G2@40K. 3 barriers. All weight fragments are
// batch-loaded and pinned with ONE asm per batch so the allocator cannot
// re-serialize the loads (each batch costs one L2 latency, not 16).
__global__ __launch_bounds__(256, 3) void k_fused(
    const float* __restrict__ inp,
    const float* __restrict__ b00, const float* __restrict__ b01,
    const float* __restrict__ b1p, const float* __restrict__ b1a,
    const float* __restrict__ b1o,
    const char* __restrict__ ws, float* __restrict__ out)
{
  __shared__ char smem[49152];
  unsigned short* G   = (unsigned short*)smem;            // 32x256, stride 512B
  unsigned short* H1m = (unsigned short*)(smem + 16384);  // 32x256, stride 512B
  unsigned short* HO  = (unsigned short*)(smem + 32768);  // 32x128, stride 256B
  unsigned short* G2  = (unsigned short*)(smem + 40960);  // 32x128, stride 256B

  // XCD-aware remap: a pair's consecutive tiles land on one XCD's L2.
  int sid = (blockIdx.x & 7) * (MAXSCHED / 8) + (blockIdx.x >> 3);
  int4 se = ((const int4*)(ws + WS_SCHED))[sid];
  int nr = se.z;
  if (nr <= 0) return;
  int p = se.x, rb = se.y;
  int e0 = p >> 3, e1 = p & 7;
  const int* rl = (const int*)(ws + WS_ROWLIST) + rb;

  const unsigned short* wt00 = (const unsigned short*)(ws + WS_WT00);
  const unsigned short* wt01 = (const unsigned short*)(ws + WS_WT01);
  const unsigned short* wt1p = (const unsigned short*)(ws + WS_WT1P);
  const unsigned short* wt1a = (const unsigned short*)(ws + WS_WT1A);
  const unsigned short* wt1o = (const unsigned short*)(ws + WS_WT1O);

  int lane = threadIdx.x & 63;
  int w    = threadIdx.x >> 6;   // wave 0..3
  int ln   = lane & 15;
  int lq   = lane >> 4;          // 0..3
  int kcol = lq * 8;

  int rowA[2];
  #pragma unroll
  for (int mt = 0; mt < 2; ++mt) {
    int rloc = mt * 16 + ln;
    rowA[mt] = (rloc < nr) ? rl[rloc] : -1;
  }

  // ---- B0: input fragments (batch) ----
  bf16x8 axf[8];  // [half*4 + mt*2 + kc]
  #pragma unroll
  for (int mt = 0; mt < 2; ++mt) {
    #pragma unroll
    for (int half = 0; half < 2; ++half) {
      #pragma unroll
      for (int kc = 0; kc < 2; ++kc) {
        bf16x8 a;
        int rg = rowA[mt];
        if (rg >= 0) {
          const float* q = inp + (size_t)rg * 144 + half * 64 + kc * 32 + kcol;
          float4 u = *(const float4*)(q);
          float4 v = *(const float4*)(q + 4);
          a[0] = (__bf16)u.x; a[1] = (__bf16)u.y; a[2] = (__bf16)u.z; a[3] = (__bf16)u.w;
          a[4] = (__bf16)v.x; a[5] = (__bf16)v.y; a[6] = (__bf16)v.z; a[7] = (__bf16)v.w;
        } else {
          #pragma unroll
          for (int j = 0; j < 8; ++j) a[j] = (__bf16)0.f;
        }
        axf[half * 4 + mt * 2 + kc] = a;
      }
    }
  }

  // ---- B1: phase-1 weights (batch of 16) ----
  bf16x8 w1f[16];  // [0..7]=W1p frag (nt*2+kc), [8..15]=W00 frag
  #pragma unroll
  for (int nt = 0; nt < 4; ++nt) {
    int n = w * 64 + nt * 16 + ln;
    #pragma unroll
    for (int kc = 0; kc < 2; ++kc) {
      w1f[nt * 2 + kc]     = *(const bf16x8*)(wt1p + ((size_t)(e1 * 256 + n) * 64 + kc * 32 + kcol));
      w1f[8 + nt * 2 + kc] = *(const bf16x8*)(wt00 + ((size_t)(e0 * 256 + n) * 64 + kc * 32 + kcol));
    }
  }
  PIN16(w1f);

  const f32x4 z4 = {0.f, 0.f, 0.f, 0.f};

  // ===== Phase 1: L1p -> G, L00 -> H1 (relu) =====
  #pragma unroll
  for (int nt = 0; nt < 4; ++nt) {
    int n = w * 64 + nt * 16 + ln;
    f32x4 acc[2] = {z4, z4};
    #pragma unroll
    for (int kc = 0; kc < 2; ++kc)
      #pragma unroll
      for (int mt = 0; mt < 2; ++mt)
        acc[mt] = __builtin_amdgcn_mfma_f32_16x16x32_bf16(axf[4 + mt * 2 + kc], w1f[nt * 2 + kc], acc[mt], 0, 0, 0);
    float bias = b1p[e1 * 256 + n];
    #pragma unroll
    for (int mt = 0; mt < 2; ++mt)
      #pragma unroll
      for (int r = 0; r < 4; ++r) {
        int row = mt * 16 + lq * 4 + r;
        float v = fmaxf(acc[mt][r] + bias, 0.f);
        G[(row * 512 + ((n << 1) ^ ((row & 7) << 4))) >> 1] = f2bf(v);
      }
  }
  #pragma unroll
  for (int nt = 0; nt < 4; ++nt) {
    int n = w * 64 + nt * 16 + ln;
    f32x4 acc[2] = {z4, z4};
    #pragma unroll
    for (int kc = 0; kc < 2; ++kc)
      #pragma unroll
      for (int mt = 0; mt < 2; ++mt)
        acc[mt] = __builtin_amdgcn_mfma_f32_16x16x32_bf16(axf[mt * 2 + kc], w1f[8 + nt * 2 + kc], acc[mt], 0, 0, 0);
    float bias = b00[e0 * 256 + n];
    #pragma unroll
    for (int mt = 0; mt < 2; ++mt)
      #pragma unroll
      for (int r = 0; r < 4; ++r) {
        int row = mt * 16 + lq * 4 + r;
        float v = fmaxf(acc[mt][r] + bias, 0.f);
        H1m[(row * 512 + ((n << 1) ^ ((row & 7) << 4))) >> 1] = f2bf(v);
      }
  }

  // ---- B2: W01 fragments (batch of 16), pinned BEFORE bar1 ----
  bf16x8 wc[16];  // [nt*8+kc]
  #pragma unroll
  for (int nt = 0; nt < 2; ++nt) {
    int n = w * 32 + nt * 16 + ln;
    #pragma unroll
    for (int kc = 0; kc < 8; ++kc)
      wc[nt * 8 + kc] = *(const bf16x8*)(wt01 + ((size_t)(e0 * 128 + n) * 256 + kc * 32 + kcol));
  }
  PIN16(wc);
  __syncthreads();  // bar1: G, H1 visible

  // ===== Phase 2a: L01: H1 @ W01 -> HO (own buffer, write immediately) =====
  f32x4 accc[2][2];
  #pragma unroll
  for (int nt = 0; nt < 2; ++nt)
    #pragma unroll
    for (int mt = 0; mt < 2; ++mt) accc[nt][mt] = z4;
  #pragma unroll
  for (int kc = 0; kc < 8; ++kc) {
    bf16x8 afr[2];
    #pragma unroll
    for (int mt = 0; mt < 2; ++mt) {
      int row = mt * 16 + ln;
      afr[mt] = *(const bf16x8*)&H1m[(row * 512 + (((kc * 32 + kcol) << 1) ^ ((row & 7) << 4))) >> 1];
    }
    #pragma unroll
    for (int nt = 0; nt < 2; ++nt)
      #pragma unroll
      for (int mt = 0; mt < 2; ++mt)
        accc[nt][mt] = __builtin_amdgcn_mfma_f32_16x16x32_bf16(afr[mt], wc[nt * 8 + kc], accc[nt][mt], 0, 0, 0);
  }
  #pragma unroll
  for (int nt = 0; nt < 2; ++nt) {
    int n = w * 32 + nt * 16 + ln;
    float bias = b01[e0 * 128 + n];
    #pragma unroll
    for (int mt = 0; mt < 2; ++mt)
      #pragma unroll
      for (int r = 0; r < 4; ++r) {
        int row = mt * 16 + lq * 4 + r;
        float v = fmaxf(accc[nt][mt][r] + bias, 0.f);
        HO[(row * 256 + ((n << 1) ^ ((row & 7) << 4))) >> 1] = f2bf(v);
      }
  }

  // ---- B3: W1a g-part fragments (batch of 16), pinned BEFORE bar2 ----
  bf16x8 wga[16];  // [nt*8+kc]
  #pragma unroll
  for (int nt = 0; nt < 2; ++nt) {
    int n = w * 32 + nt * 16 + ln;
    #pragma unroll
    for (int kc = 0; kc < 8; ++kc)
      wga[nt * 8 + kc] = *(const bf16x8*)(wt1a + ((size_t)(e1 * 128 + n) * 384 + 128 + kc * 32 + kcol));
  }
  PIN16(wga);
  __syncthreads();  // bar2: HO visible

  // ===== Phase 2b: L1a-partial: G @ W1a-g -> acc1a =====
  f32x4 acc1a[2][2];
  #pragma unroll
  for (int nt = 0; nt < 2; ++nt)
    #pragma unroll
    for (int mt = 0; mt < 2; ++mt) acc1a[nt][mt] = z4;
  #pragma unroll
  for (int kc = 0; kc < 8; ++kc) {
    bf16x8 afr[2];
    #pragma unroll
    for (int mt = 0; mt < 2; ++mt) {
      int row = mt * 16 + ln;
      afr[mt] = *(const bf16x8*)&G[(row * 512 + (((kc * 32 + kcol) << 1) ^ ((row & 7) << 4))) >> 1];
    }
    #pragma unroll
    for (int nt = 0; nt < 2; ++nt)
      #pragma unroll
      for (int mt = 0; mt < 2; ++mt)
        acc1a[nt][mt] = __builtin_amdgcn_mfma_f32_16x16x32_bf16(afr[mt], wga[nt * 8 + kc], acc1a[nt][mt], 0, 0, 0);
  }

  // ---- B4: W1a h-part + W1o fragments (batch of 12) ----
  bf16x8 who[12];  // [0..7]=W1a-h (nt*4+kc), [8..11]=W1o (kc)
  #pragma unroll
  for (int nt = 0; nt < 2; ++nt) {
    int n = w * 32 + nt * 16 + ln;
    #pragma unroll
    for (int kc = 0; kc < 4; ++kc)
      who[nt * 4 + kc] = *(const bf16x8*)(wt1a + ((size_t)(e1 * 128 + n) * 384 + kc * 32 + kcol));
  }
  {
    int n = (w >> 1) * 16 + ln;
    #pragma unroll
    for (int kc = 0; kc < 4; ++kc)
      who[8 + kc] = *(const bf16x8*)(wt1o + ((size_t)(e1 * 32 + n) * 128 + kc * 32 + kcol));
  }
  PIN12(who);

  // ===== L1a-finish: HO @ W1a-h -> acc1a; relu -> G2 =====
  #pragma unroll
  for (int kc = 0; kc < 4; ++kc) {
    bf16x8 afr[2];
    #pragma unroll
    for (int mt = 0; mt < 2; ++mt) {
      int row = mt * 16 + ln;
      afr[mt] = *(const bf16x8*)&HO[(row * 256 + (((kc * 32 + kcol) << 1) ^ ((row & 7) << 4))) >> 1];
    }
    #pragma unroll
    for (int nt = 0; nt < 2; ++nt)
      #pragma unroll
      for (int mt = 0; mt < 2; ++mt)
        acc1a[nt][mt] = __builtin_amdgcn_mfma_f32_16x16x32_bf16(afr[mt], who[nt * 4 + kc], acc1a[nt][mt], 0, 0, 0);
  }
  #pragma unroll
  for (int nt = 0; nt < 2; ++nt) {
    int n = w * 32 + nt * 16 + ln;
    float bias = b1a[e1 * 128 + n];
    #pragma unroll
    for (int mt = 0; mt < 2; ++mt)
      #pragma unroll
      for (int r = 0; r < 4; ++r) {
        int row = mt * 16 + lq * 4 + r;
        float v = fmaxf(acc1a[nt][mt][r] + bias, 0.f);
        G2[(row * 256 + ((n << 1) ^ ((row & 7) << 4))) >> 1] = f2bf(v);
      }
  }
  __syncthreads();  // bar3: G2 visible

  // ===== Phase 3: L1o: G2 @ W1o -> out (32), no relu, fp32 scatter =====
  {
    int mt = w & 1;
    int n  = (w >> 1) * 16 + ln;
    f32x4 acc = z4;
    #pragma unroll
    for (int kc = 0; kc < 4; ++kc) {
      int row = mt * 16 + ln;
      bf16x8 afr = *(const bf16x8*)&G2[(row * 256 + (((kc * 32 + kcol) << 1) ^ ((row & 7) << 4))) >> 1];
      acc = __builtin_amdgcn_mfma_f32_16x16x32_bf16(afr, who[8 + kc], acc, 0, 0, 0);
    }
    float bias = b1o[e1 * 32 + n];
    #pragma unroll
    for (int r = 0; r < 4; ++r) {
      int row = mt * 16 + lq * 4 + r;
      if (row < nr) {
        int rg = rl[row];
        out[(size_t)rg * 32 + n] = acc[r] + bias;
      }
    }
  }
}

extern "C" void kernel_launch(void* const* d_in, const int* in_sizes, int n_in,
                              void* d_out, int out_size, void* d_ws, size_t ws_size,
                              hipStream_t stream) {
  const float* inp = (const float*)d_in[0];
  const float* w00 = (const float*)d_in[1];
  const float* b00 = (const float*)d_in[2];
  const float* w01 = (const float*)d_in[3];
  const float* b01 = (const float*)d_in[4];
  const float* w1p = (const float*)d_in[5];
  const float* b1p = (const float*)d_in[6];
  const float* w1a = (const float*)d_in[7];
  const float* b1a = (const float*)d_in[8];
  const float* w1o = (const float*)d_in[9];
  const float* b1o = (const float*)d_in[10];
  char*  ws  = (char*)d_ws;
  float* out = (float*)d_out;

  k_combo<<<368, 256, 0, stream>>>(w00, w01, w1p, w1a, w1o, inp, ws);
  k_scan<<<1, 1024, 0, stream>>>((const int*)(ws + WS_BH), (int*)(ws + WS_OFF),
                                 (int4*)(ws + WS_SCHED));
  k_scatter<<<NBLK, 256, 0, stream>>>((const int*)(ws + WS_PAIR),
                                      (const int*)(ws + WS_OFF),
                                      (int*)(ws + WS_ROWLIST));
  k_fused<<<MAXSCHED, 256, 0, stream>>>(inp, b00, b01, b1p, b1a, b1o, ws, out);
}

// Round 6
// 56.359 us; speedup vs baseline: 1.2377x; 1.1497x over previous
//
#include <hip/hip_runtime.h>
#include <hip/hip_bf16.h>

#define BATCH     32768
#define TILE      32
#define NPAIR     64
#define NBLK      128          /* route blocks: BATCH/256 */

typedef __bf16 bf16x8 __attribute__((ext_vector_type(8)));
typedef float  f32x4  __attribute__((ext_vector_type(4)));
static_assert(sizeof(bf16x8) == 16, "bf16x8 must be 16B");

// ---- workspace byte offsets ----
#define WS_CNT      0
#define WS_BASE     256
#define WS_BH       1024
#define WS_OFF      (WS_BH + NBLK*NPAIR*4)
#define WS_PAIR     (WS_OFF + NBLK*NPAIR*4)
#define WS_ROWLIST  (WS_PAIR + BATCH*4)
#define WS_WT00     (WS_ROWLIST + BATCH*4)
#define WS_WT01     (WS_WT00 + 131072*2)
#define WS_WT1P     (WS_WT01 + 262144*2)
#define WS_WT1A     (WS_WT1P + 131072*2)
#define WS_WT1O     (WS_WT1A + 393216*2)

__device__ __forceinline__ unsigned short f2bf(float x) {
  __bf16 h = (__bf16)x;
  return __builtin_bit_cast(unsigned short, h);
}

// Identity pin: value becomes an asm result -> cannot be rematerialized as a
// load inside the tile loop; forces register residency across the loop.
#define KEEP(x) asm volatile("" : "+v"(x))

// Merged: blocks 0..239 transpose weights fp32->bf16 [m][o][i]; blocks 240..367 route.
__global__ __launch_bounds__(256) void k_combo(const float* __restrict__ w00,
                                               const float* __restrict__ w01,
                                               const float* __restrict__ w1p,
                                               const float* __restrict__ w1a,
                                               const float* __restrict__ w1o,
                                               const float* __restrict__ inp,
                                               char* __restrict__ ws) {
  __shared__ unsigned short lds[64 * 72];
  int bid = blockIdx.x;
  if (bid >= 240) {
    int* h = (int*)lds;
    int rbid = bid - 240;
    int t = threadIdx.x;
    if (t < NPAIR) h[t] = 0;
    __syncthreads();
    int r = rbid * 256 + t;
    const float* q = inp + (size_t)r * 144 + 128;
    float4 u0 = *(const float4*)(q + 0);
    float4 u1 = *(const float4*)(q + 4);
    float4 v0 = *(const float4*)(q + 8);
    float4 v1 = *(const float4*)(q + 12);
    int a0 = 0;
    if (u0.y > 0.5f) a0 = 1; if (u0.z > 0.5f) a0 = 2; if (u0.w > 0.5f) a0 = 3;
    if (u1.x > 0.5f) a0 = 4; if (u1.y > 0.5f) a0 = 5; if (u1.z > 0.5f) a0 = 6; if (u1.w > 0.5f) a0 = 7;
    int a1 = 0;
    if (v0.y > 0.5f) a1 = 1; if (v0.z > 0.5f) a1 = 2; if (v0.w > 0.5f) a1 = 3;
    if (v1.x > 0.5f) a1 = 4; if (v1.y > 0.5f) a1 = 5; if (v1.z > 0.5f) a1 = 6; if (v1.w > 0.5f) a1 = 7;
    int p = a0 * 8 + a1;
    ((int*)(ws + WS_PAIR))[r] = p;
    atomicAdd(&h[p], 1);
    __syncthreads();
    if (t < NPAIR) ((int*)(ws + WS_BH))[rbid * NPAIR + t] = h[t];
    return;
  }
  const float* src; unsigned short* dst; int I, O, lt;
  if (bid < 32)       { src = w00; dst = (unsigned short*)(ws + WS_WT00); I = 64;  O = 256; lt = bid; }
  else if (bid < 96)  { src = w01; dst = (unsigned short*)(ws + WS_WT01); I = 256; O = 128; lt = bid - 32; }
  else if (bid < 128) { src = w1p; dst = (unsigned short*)(ws + WS_WT1P); I = 64;  O = 256; lt = bid - 96; }
  else if (bid < 224) { src = w1a; dst = (unsigned short*)(ws + WS_WT1A); I = 384; O = 128; lt = bid - 128; }
  else                { src = w1o; dst = (unsigned short*)(ws + WS_WT1O); I = 128; O = 32;  lt = bid - 224; }
  int tI = I >> 6;
  int tO = (O + 63) >> 6;
  int m   = lt / (tI * tO);
  int rem = lt % (tI * tO);
  int ib = rem / tO, ob = rem % tO;
  int tx = threadIdx.x & 63, ty = threadIdx.x >> 6;
  const float* s = src + (size_t)m * I * O;
  #pragma unroll 4
  for (int s4 = 0; s4 < 16; ++s4) {
    int li = s4 * 4 + ty;
    int o  = ob * 64 + tx;
    float v = (o < O) ? s[(size_t)(ib * 64 + li) * O + o] : 0.f;
    lds[li * 72 + tx] = f2bf(v);
  }
  __syncthreads();
  unsigned short* d = dst + (size_t)m * O * I;
  #pragma unroll 4
  for (int s4 = 0; s4 < 16; ++s4) {
    int lo = s4 * 4 + ty;
    int o  = ob * 64 + lo;
    if (o < O) d[(size_t)o * I + ib * 64 + tx] = lds[tx * 72 + lo];
  }
}

// Scan: 1 block x 1024 threads. Outputs cnt[p], base[p], per-(block,pair) off.
__global__ __launch_bounds__(1024) void k_scan(const int* __restrict__ bh,
                                               int* __restrict__ cnt,
                                               int* __restrict__ base,
                                               int* __restrict__ off) {
  __shared__ int part[16][NPAIR];
  __shared__ int bs64[NPAIR];
  int tid = threadIdx.x;
  int p = tid & 63, c = tid >> 6;
  int loc[8]; int s = 0;
  #pragma unroll
  for (int i = 0; i < 8; ++i) { loc[i] = s; s += bh[(c * 8 + i) * NPAIR + p]; }
  part[c][p] = s;
  __syncthreads();
  if (tid < 64) {
    int run = 0;
    #pragma unroll
    for (int c2 = 0; c2 < 16; ++c2) { int v = part[c2][p]; part[c2][p] = run; run += v; }
    cnt[p] = run;
    int x = run;
    #pragma unroll
    for (int d = 1; d < 64; d <<= 1) { int y = __shfl_up(x, d); if (p >= d) x += y; }
    int bs = x - run;
    base[p] = bs;
    bs64[p] = bs;
  }
  __syncthreads();
  int add = part[c][p] + bs64[p];
  #pragma unroll
  for (int i = 0; i < 8; ++i) off[(c * 8 + i) * NPAIR + p] = loc[i] + add;
}

// Scatter: LDS-local rank + precomputed global offset. NO global atomics.
__global__ __launch_bounds__(256) void k_scatter(const int* __restrict__ pairArr,
                                                 const int* __restrict__ off,
                                                 int* __restrict__ rowlist) {
  __shared__ int h[NPAIR];
  int t = threadIdx.x;
  if (t < NPAIR) h[t] = 0;
  __syncthreads();
  int r = blockIdx.x * 256 + threadIdx.x;
  int p = pairArr[r];
  int rank = atomicAdd(&h[p], 1);
  rowlist[off[blockIdx.x * NPAIR + p] + rank] = r;
}

// Persistent pair blocks: 256 blocks (1/CU), 8 waves, block owns pair bid>>2,
// slice bid&3, loops tiles t = slice, slice+4, ... of 32 rows. All weight
// fragments are loop-invariant, loaded ONCE, pinned in registers via KEEP.
// LDS 48KB: G@0 (32x256 s512), H1@16K, HO@32K (32x128 s256), G2@40K.
// Swizzle byte ^= (row&7)<<4 everywhere (same as verified R5 math).
__global__ __launch_bounds__(512, 2) void k_fused(
    const float* __restrict__ inp,
    const float* __restrict__ b00, const float* __restrict__ b01,
    const float* __restrict__ b1p, const float* __restrict__ b1a,
    const float* __restrict__ b1o,
    const char* __restrict__ ws, float* __restrict__ out)
{
  __shared__ char smem[49152];
  unsigned short* G   = (unsigned short*)smem;
  unsigned short* H1m = (unsigned short*)(smem + 16384);
  unsigned short* HO  = (unsigned short*)(smem + 32768);
  unsigned short* G2  = (unsigned short*)(smem + 40960);

  int p     = blockIdx.x >> 2;
  int slice = blockIdx.x & 3;
  int e0 = p >> 3, e1 = p & 7;
  int cnt = ((const int*)(ws + WS_CNT))[p];
  if (cnt == 0) return;
  int base = ((const int*)(ws + WS_BASE))[p];
  const int* rlbase = (const int*)(ws + WS_ROWLIST) + base;

  const unsigned short* wt00 = (const unsigned short*)(ws + WS_WT00);
  const unsigned short* wt01 = (const unsigned short*)(ws + WS_WT01);
  const unsigned short* wt1p = (const unsigned short*)(ws + WS_WT1P);
  const unsigned short* wt1a = (const unsigned short*)(ws + WS_WT1A);
  const unsigned short* wt1o = (const unsigned short*)(ws + WS_WT1O);

  int lane = threadIdx.x & 63;
  int w    = threadIdx.x >> 6;   // wave 0..7
  int ln   = lane & 15;
  int lq   = lane >> 4;
  int kcol = lq * 8;

  // ---- hoisted weight fragments (loop-invariant, pinned) ----
  bf16x8 w1pf[2][2], w00f[2][2];     // n = w*32 + nt*16 + ln, kc 0..1
  #pragma unroll
  for (int nt = 0; nt < 2; ++nt) {
    int n = w * 32 + nt * 16 + ln;
    #pragma unroll
    for (int kc = 0; kc < 2; ++kc) {
      w1pf[nt][kc] = *(const bf16x8*)(wt1p + ((size_t)(e1 * 256 + n) * 64 + kc * 32 + kcol));
      w00f[nt][kc] = *(const bf16x8*)(wt00 + ((size_t)(e0 * 256 + n) * 64 + kc * 32 + kcol));
    }
  }
  bf16x8 wc[8];                      // W01, n = w*16 + ln, kc 0..7
  #pragma unroll
  for (int kc = 0; kc < 8; ++kc)
    wc[kc] = *(const bf16x8*)(wt01 + ((size_t)(e0 * 128 + w * 16 + ln) * 256 + kc * 32 + kcol));
  bf16x8 wa[12];                     // W1a, n = w*16 + ln, kc 0..11 (k = kc*32)
  #pragma unroll
  for (int kc = 0; kc < 12; ++kc)
    wa[kc] = *(const bf16x8*)(wt1a + ((size_t)(e1 * 128 + w * 16 + ln) * 384 + kc * 32 + kcol));
  bf16x8 wo[4];                      // W1o, waves 0..3 only: mt=w&1, n=(w>>1)*16+ln
  if (w < 4) {
    #pragma unroll
    for (int kc = 0; kc < 4; ++kc)
      wo[kc] = *(const bf16x8*)(wt1o + ((size_t)(e1 * 32 + (w >> 1) * 16 + ln) * 128 + kc * 32 + kcol));
  }

  #pragma unroll
  for (int nt = 0; nt < 2; ++nt)
    #pragma unroll
    for (int kc = 0; kc < 2; ++kc) { KEEP(w1pf[nt][kc]); KEEP(w00f[nt][kc]); }
  #pragma unroll
  for (int kc = 0; kc < 8; ++kc) KEEP(wc[kc]);
  #pragma unroll
  for (int kc = 0; kc < 12; ++kc) KEEP(wa[kc]);
  if (w < 4) {
    #pragma unroll
    for (int kc = 0; kc < 4; ++kc) KEEP(wo[kc]);
  }

  // hoisted biases
  float bias1p[2], bias00[2];
  #pragma unroll
  for (int nt = 0; nt < 2; ++nt) {
    int n = w * 32 + nt * 16 + ln;
    bias1p[nt] = b1p[e1 * 256 + n];
    bias00[nt] = b00[e0 * 256 + n];
  }
  float bias01 = b01[e0 * 128 + w * 16 + ln];
  float bias1a = b1a[e1 * 128 + w * 16 + ln];
  float bias1o = (w < 4) ? b1o[e1 * 32 + (w >> 1) * 16 + ln] : 0.f;

  const f32x4 z4 = {0.f, 0.f, 0.f, 0.f};
  int ntiles = (cnt + 31) >> 5;

  for (int t = slice; t < ntiles; t += 4) {
    int nr = min(32, cnt - t * 32);
    const int* rl = rlbase + t * 32;

    int rowA[2];
    #pragma unroll
    for (int mt = 0; mt < 2; ++mt) {
      int rloc = mt * 16 + ln;
      rowA[mt] = (rloc < nr) ? rl[rloc] : -1;
    }

    // input fragments
    bf16x8 axf[2][2][2];  // [half][mt][kc]
    #pragma unroll
    for (int mt = 0; mt < 2; ++mt) {
      #pragma unroll
      for (int half = 0; half < 2; ++half) {
        #pragma unroll
        for (int kc = 0; kc < 2; ++kc) {
          bf16x8 a;
          int rg = rowA[mt];
          if (rg >= 0) {
            const float* q = inp + (size_t)rg * 144 + half * 64 + kc * 32 + kcol;
            float4 u = *(const float4*)(q);
            float4 v = *(const float4*)(q + 4);
            a[0] = (__bf16)u.x; a[1] = (__bf16)u.y; a[2] = (__bf16)u.z; a[3] = (__bf16)u.w;
            a[4] = (__bf16)v.x; a[5] = (__bf16)v.y; a[6] = (__bf16)v.z; a[7] = (__bf16)v.w;
          } else {
            #pragma unroll
            for (int j = 0; j < 8; ++j) a[j] = (__bf16)0.f;
          }
          axf[half][mt][kc] = a;
        }
      }
    }

    // ===== P1: L1p -> G, L00 -> H1 =====
    #pragma unroll
    for (int nt = 0; nt < 2; ++nt) {
      int n = w * 32 + nt * 16 + ln;
      f32x4 acc[2] = {z4, z4};
      #pragma unroll
      for (int kc = 0; kc < 2; ++kc)
        #pragma unroll
        for (int mt = 0; mt < 2; ++mt)
          acc[mt] = __builtin_amdgcn_mfma_f32_16x16x32_bf16(axf[1][mt][kc], w1pf[nt][kc], acc[mt], 0, 0, 0);
      #pragma unroll
      for (int mt = 0; mt < 2; ++mt)
        #pragma unroll
        for (int r = 0; r < 4; ++r) {
          int row = mt * 16 + lq * 4 + r;
          float v = fmaxf(acc[mt][r] + bias1p[nt], 0.f);
          G[(row * 512 + ((n << 1) ^ ((row & 7) << 4))) >> 1] = f2bf(v);
        }
    }
    #pragma unroll
    for (int nt = 0; nt < 2; ++nt) {
      int n = w * 32 + nt * 16 + ln;
      f32x4 acc[2] = {z4, z4};
      #pragma unroll
      for (int kc = 0; kc < 2; ++kc)
        #pragma unroll
        for (int mt = 0; mt < 2; ++mt)
          acc[mt] = __builtin_amdgcn_mfma_f32_16x16x32_bf16(axf[0][mt][kc], w00f[nt][kc], acc[mt], 0, 0, 0);
      #pragma unroll
      for (int mt = 0; mt < 2; ++mt)
        #pragma unroll
        for (int r = 0; r < 4; ++r) {
          int row = mt * 16 + lq * 4 + r;
          float v = fmaxf(acc[mt][r] + bias00[nt], 0.f);
          H1m[(row * 512 + ((n << 1) ^ ((row & 7) << 4))) >> 1] = f2bf(v);
        }
    }
    __syncthreads();

    // ===== P2: L01: H1 @ wc -> HO =====
    {
      f32x4 accc[2] = {z4, z4};
      #pragma unroll
      for (int kc = 0; kc < 8; ++kc) {
        bf16x8 afr[2];
        #pragma unroll
        for (int mt = 0; mt < 2; ++mt) {
          int row = mt * 16 + ln;
          afr[mt] = *(const bf16x8*)&H1m[(row * 512 + (((kc * 32 + kcol) << 1) ^ ((row & 7) << 4))) >> 1];
        }
        #pragma unroll
        for (int mt = 0; mt < 2; ++mt)
          accc[mt] = __builtin_amdgcn_mfma_f32_16x16x32_bf16(afr[mt], wc[kc], accc[mt], 0, 0, 0);
      }
      int n = w * 16 + ln;
      #pragma unroll
      for (int mt = 0; mt < 2; ++mt)
        #pragma unroll
        for (int r = 0; r < 4; ++r) {
          int row = mt * 16 + lq * 4 + r;
          float v = fmaxf(accc[mt][r] + bias01, 0.f);
          HO[(row * 256 + ((n << 1) ^ ((row & 7) << 4))) >> 1] = f2bf(v);
        }
    }
    __syncthreads();

    // ===== P3: L1a: [HO | G] @ wa -> G2 =====
    {
      f32x4 acc1a[2] = {z4, z4};
      #pragma unroll
      for (int kc = 0; kc < 4; ++kc) {
        bf16x8 afr[2];
        #pragma unroll
        for (int mt = 0; mt < 2; ++mt) {
          int row = mt * 16 + ln;
          afr[mt] = *(const bf16x8*)&HO[(row * 256 + (((kc * 32 + kcol) << 1) ^ ((row & 7) << 4))) >> 1];
        }
        #pragma unroll
        for (int mt = 0; mt < 2; ++mt)
          acc1a[mt] = __builtin_amdgcn_mfma_f32_16x16x32_bf16(afr[mt], wa[kc], acc1a[mt], 0, 0, 0);
      }
      #pragma unroll
      for (int kc = 4; kc < 12; ++kc) {
        int kk = kc - 4;
        bf16x8 afr[2];
        #pragma unroll
        for (int mt = 0; mt < 2; ++mt) {
          int row = mt * 16 + ln;
          afr[mt] = *(const bf16x8*)&G[(row * 512 + (((kk * 32 + kcol) << 1) ^ ((row & 7) << 4))) >> 1];
        }
        #pragma unroll
        for (int mt = 0; mt < 2; ++mt)
          acc1a[mt] = __builtin_amdgcn_mfma_f32_16x16x32_bf16(afr[mt], wa[kc], acc1a[mt], 0, 0, 0);
      }
      int n = w * 16 + ln;
      #pragma unroll
      for (int mt = 0; mt < 2; ++mt)
        #pragma unroll
        for (int r = 0; r < 4; ++r) {
          int row = mt * 16 + lq * 4 + r;
          float v = fmaxf(acc1a[mt][r] + bias1a, 0.f);
          G2[(row * 256 + ((n << 1) ^ ((row & 7) << 4))) >> 1] = f2bf(v);
        }
    }
    __syncthreads();

    // ===== P4: L1o (waves 0..3): G2 @ wo -> out =====
    if (w < 4) {
      int mt = w & 1;
      int n  = (w >> 1) * 16 + ln;
      f32x4 acc = z4;
      #pragma unroll
      for (int kc = 0; kc < 4; ++kc) {
        int row = mt * 16 + ln;
        bf16x8 afr = *(const bf16x8*)&G2[(row * 256 + (((kc * 32 + kcol) << 1) ^ ((row & 7) << 4))) >> 1];
        acc = __builtin_amdgcn_mfma_f32_16x16x32_bf16(afr, wo[kc], acc, 0, 0, 0);
      }
      #pragma unroll
      for (int r = 0; r < 4; ++r) {
        int row = mt * 16 + lq * 4 + r;
        if (row < nr) {
          int rg = rl[row];
          out[(size_t)rg * 32 + n] = acc[r] + bias1o;
        }
      }
    }
    __syncthreads();
  }
}

extern "C" void kernel_launch(void* const* d_in, const int* in_sizes, int n_in,
                              void* d_out, int out_size, void* d_ws, size_t ws_size,
                              hipStream_t stream) {
  const float* inp = (const float*)d_in[0];
  const float* w00 = (const float*)d_in[1];
  const float* b00 = (const float*)d_in[2];
  const float* w01 = (const float*)d_in[3];
  const float* b01 = (const float*)d_in[4];
  const float* w1p = (const float*)d_in[5];
  const float* b1p = (const float*)d_in[6];
  const float* w1a = (const float*)d_in[7];
  const float* b1a = (const float*)d_in[8];
  const float* w1o = (const float*)d_in[9];
  const float* b1o = (const float*)d_in[10];
  char*  ws  = (char*)d_ws;
  float* out = (float*)d_out;

  k_combo<<<368, 256, 0, stream>>>(w00, w01, w1p, w1a, w1o, inp, ws);
  k_scan<<<1, 1024, 0, stream>>>((const int*)(ws + WS_BH), (int*)(ws + WS_CNT),
                                 (int*)(ws + WS_BASE), (int*)(ws + WS_OFF));
  k_scatter<<<NBLK, 256, 0, stream>>>((const int*)(ws + WS_PAIR),
                                      (const int*)(ws + WS_OFF),
                                      (int*)(ws + WS_ROWLIST));
  k_fused<<<256, 512, 0, stream>>>(inp, b00, b01, b1p, b1a, b1o, ws, out);
}

// Round 7
// 55.132 us; speedup vs baseline: 1.2653x; 1.0222x over previous
//
#include <hip/hip_runtime.h>
#include <hip/hip_bf16.h>

#define BATCH     32768
#define TILE      32
#define NPAIR     64
#define NBLK      128          /* route blocks: BATCH/256 */

typedef __bf16 bf16x8 __attribute__((ext_vector_type(8)));
typedef float  f32x4  __attribute__((ext_vector_type(4)));
static_assert(sizeof(bf16x8) == 16, "bf16x8 must be 16B");

// ---- workspace byte offsets ----
#define WS_CNT      0
#define WS_BASE     256
#define WS_BH       1024
#define WS_OFF      (WS_BH + NBLK*NPAIR*4)
#define WS_PAIR     (WS_OFF + NBLK*NPAIR*4)
#define WS_ROWLIST  (WS_PAIR + BATCH*4)
#define WS_WT00     (WS_ROWLIST + BATCH*4)
#define WS_WT01     (WS_WT00 + 131072*2)
#define WS_WT1P     (WS_WT01 + 262144*2)
#define WS_WT1A     (WS_WT1P + 131072*2)
#define WS_WT1O     (WS_WT1A + 393216*2)

__device__ __forceinline__ unsigned short f2bf(float x) {
  __bf16 h = (__bf16)x;
  return __builtin_bit_cast(unsigned short, h);
}

// Identity pin: value becomes an asm result -> cannot be rematerialized as a
// load later; with a generous VGPR cap the allocator keeps it resident.
#define KEEP(x) asm volatile("" : "+v"(x))

// Merged: blocks 0..239 transpose weights fp32->bf16 [m][o][i]; blocks 240..367 route.
__global__ __launch_bounds__(256) void k_combo(const float* __restrict__ w00,
                                               const float* __restrict__ w01,
                                               const float* __restrict__ w1p,
                                               const float* __restrict__ w1a,
                                               const float* __restrict__ w1o,
                                               const float* __restrict__ inp,
                                               char* __restrict__ ws) {
  __shared__ unsigned short lds[64 * 72];
  int bid = blockIdx.x;
  if (bid >= 240) {
    int* h = (int*)lds;
    int rbid = bid - 240;
    int t = threadIdx.x;
    if (t < NPAIR) h[t] = 0;
    __syncthreads();
    int r = rbid * 256 + t;
    const float* q = inp + (size_t)r * 144 + 128;
    float4 u0 = *(const float4*)(q + 0);
    float4 u1 = *(const float4*)(q + 4);
    float4 v0 = *(const float4*)(q + 8);
    float4 v1 = *(const float4*)(q + 12);
    int a0 = 0;
    if (u0.y > 0.5f) a0 = 1; if (u0.z > 0.5f) a0 = 2; if (u0.w > 0.5f) a0 = 3;
    if (u1.x > 0.5f) a0 = 4; if (u1.y > 0.5f) a0 = 5; if (u1.z > 0.5f) a0 = 6; if (u1.w > 0.5f) a0 = 7;
    int a1 = 0;
    if (v0.y > 0.5f) a1 = 1; if (v0.z > 0.5f) a1 = 2; if (v0.w > 0.5f) a1 = 3;
    if (v1.x > 0.5f) a1 = 4; if (v1.y > 0.5f) a1 = 5; if (v1.z > 0.5f) a1 = 6; if (v1.w > 0.5f) a1 = 7;
    int p = a0 * 8 + a1;
    ((int*)(ws + WS_PAIR))[r] = p;
    atomicAdd(&h[p], 1);
    __syncthreads();
    if (t < NPAIR) ((int*)(ws + WS_BH))[rbid * NPAIR + t] = h[t];
    return;
  }
  const float* src; unsigned short* dst; int I, O, lt;
  if (bid < 32)       { src = w00; dst = (unsigned short*)(ws + WS_WT00); I = 64;  O = 256; lt = bid; }
  else if (bid < 96)  { src = w01; dst = (unsigned short*)(ws + WS_WT01); I = 256; O = 128; lt = bid - 32; }
  else if (bid < 128) { src = w1p; dst = (unsigned short*)(ws + WS_WT1P); I = 64;  O = 256; lt = bid - 96; }
  else if (bid < 224) { src = w1a; dst = (unsigned short*)(ws + WS_WT1A); I = 384; O = 128; lt = bid - 128; }
  else                { src = w1o; dst = (unsigned short*)(ws + WS_WT1O); I = 128; O = 32;  lt = bid - 224; }
  int tI = I >> 6;
  int tO = (O + 63) >> 6;
  int m   = lt / (tI * tO);
  int rem = lt % (tI * tO);
  int ib = rem / tO, ob = rem % tO;
  int tx = threadIdx.x & 63, ty = threadIdx.x >> 6;
  const float* s = src + (size_t)m * I * O;
  #pragma unroll 4
  for (int s4 = 0; s4 < 16; ++s4) {
    int li = s4 * 4 + ty;
    int o  = ob * 64 + tx;
    float v = (o < O) ? s[(size_t)(ib * 64 + li) * O + o] : 0.f;
    lds[li * 72 + tx] = f2bf(v);
  }
  __syncthreads();
  unsigned short* d = dst + (size_t)m * O * I;
  #pragma unroll 4
  for (int s4 = 0; s4 < 16; ++s4) {
    int lo = s4 * 4 + ty;
    int o  = ob * 64 + lo;
    if (o < O) d[(size_t)o * I + ib * 64 + tx] = lds[tx * 72 + lo];
  }
}

// Scan: 1 block x 1024 threads. Outputs cnt[p], base[p], per-(block,pair) off.
__global__ __launch_bounds__(1024) void k_scan(const int* __restrict__ bh,
                                               int* __restrict__ cnt,
                                               int* __restrict__ base,
                                               int* __restrict__ off) {
  __shared__ int part[16][NPAIR];
  __shared__ int bs64[NPAIR];
  int tid = threadIdx.x;
  int p = tid & 63, c = tid >> 6;
  int loc[8]; int s = 0;
  #pragma unroll
  for (int i = 0; i < 8; ++i) { loc[i] = s; s += bh[(c * 8 + i) * NPAIR + p]; }
  part[c][p] = s;
  __syncthreads();
  if (tid < 64) {
    int run = 0;
    #pragma unroll
    for (int c2 = 0; c2 < 16; ++c2) { int v = part[c2][p]; part[c2][p] = run; run += v; }
    cnt[p] = run;
    int x = run;
    #pragma unroll
    for (int d = 1; d < 64; d <<= 1) { int y = __shfl_up(x, d); if (p >= d) x += y; }
    int bs = x - run;
    base[p] = bs;
    bs64[p] = bs;
  }
  __syncthreads();
  int add = part[c][p] + bs64[p];
  #pragma unroll
  for (int i = 0; i < 8; ++i) off[(c * 8 + i) * NPAIR + p] = loc[i] + add;
}

// Scatter: LDS-local rank + precomputed global offset. NO global atomics.
__global__ __launch_bounds__(256) void k_scatter(const int* __restrict__ pairArr,
                                                 const int* __restrict__ off,
                                                 int* __restrict__ rowlist) {
  __shared__ int h[NPAIR];
  int t = threadIdx.x;
  if (t < NPAIR) h[t] = 0;
  __syncthreads();
  int r = blockIdx.x * 256 + threadIdx.x;
  int p = pairArr[r];
  int rank = atomicAdd(&h[p], 1);
  rowlist[off[blockIdx.x * NPAIR + p] + rank] = r;
}

// Persistent pair blocks: 256 blocks (1/CU), 8 waves, block owns pair bid>>2,
// slice bid&3, loops tiles t = slice, +4, ... of 32 rows. Weight fragments are
// loop-invariant, loaded ONCE, pinned (KEEP). launch_bounds(512,1) so the
// allocator may use ~240 VGPR without spilling. Input gather for tile t+4 is
// prefetched during tile t (pinned before bar1). 3 barriers/tile (G2 is
// private, so no end-of-loop barrier: waves 4-7 start next P1 during P4).
// LDS 48KB: G@0 (32x256 s512), H1@16K, HO@32K (32x128 s256), G2@40K.
// Swizzle byte ^= (row&7)<<4 everywhere (same verified math since R5).
__global__ __launch_bounds__(512, 1) void k_fused(
    const float* __restrict__ inp,
    const float* __restrict__ b00, const float* __restrict__ b01,
    const float* __restrict__ b1p, const float* __restrict__ b1a,
    const float* __restrict__ b1o,
    const char* __restrict__ ws, float* __restrict__ out)
{
  __shared__ char smem[49152];
  unsigned short* G   = (unsigned short*)smem;
  unsigned short* H1m = (unsigned short*)(smem + 16384);
  unsigned short* HO  = (unsigned short*)(smem + 32768);
  unsigned short* G2  = (unsigned short*)(smem + 40960);

  int p     = blockIdx.x >> 2;
  int slice = blockIdx.x & 3;
  int e0 = p >> 3, e1 = p & 7;
  int cnt = ((const int*)(ws + WS_CNT))[p];
  int base = ((const int*)(ws + WS_BASE))[p];
  const int* rlbase = (const int*)(ws + WS_ROWLIST) + base;
  int ntiles = (cnt + 31) >> 5;
  if (slice >= ntiles) return;

  const unsigned short* wt00 = (const unsigned short*)(ws + WS_WT00);
  const unsigned short* wt01 = (const unsigned short*)(ws + WS_WT01);
  const unsigned short* wt1p = (const unsigned short*)(ws + WS_WT1P);
  const unsigned short* wt1a = (const unsigned short*)(ws + WS_WT1A);
  const unsigned short* wt1o = (const unsigned short*)(ws + WS_WT1O);

  int lane = threadIdx.x & 63;
  int w    = threadIdx.x >> 6;   // wave 0..7
  int ln   = lane & 15;
  int lq   = lane >> 4;
  int kcol = lq * 8;

  // ---- hoisted weight fragments (loop-invariant, pinned) ----
  bf16x8 w1pf[2][2], w00f[2][2];
  #pragma unroll
  for (int nt = 0; nt < 2; ++nt) {
    int n = w * 32 + nt * 16 + ln;
    #pragma unroll
    for (int kc = 0; kc < 2; ++kc) {
      w1pf[nt][kc] = *(const bf16x8*)(wt1p + ((size_t)(e1 * 256 + n) * 64 + kc * 32 + kcol));
      w00f[nt][kc] = *(const bf16x8*)(wt00 + ((size_t)(e0 * 256 + n) * 64 + kc * 32 + kcol));
    }
  }
  bf16x8 wc[8];
  #pragma unroll
  for (int kc = 0; kc < 8; ++kc)
    wc[kc] = *(const bf16x8*)(wt01 + ((size_t)(e0 * 128 + w * 16 + ln) * 256 + kc * 32 + kcol));
  bf16x8 wa[12];
  #pragma unroll
  for (int kc = 0; kc < 12; ++kc)
    wa[kc] = *(const bf16x8*)(wt1a + ((size_t)(e1 * 128 + w * 16 + ln) * 384 + kc * 32 + kcol));
  bf16x8 wo[4];
  if (w < 4) {
    #pragma unroll
    for (int kc = 0; kc < 4; ++kc)
      wo[kc] = *(const bf16x8*)(wt1o + ((size_t)(e1 * 32 + (w >> 1) * 16 + ln) * 128 + kc * 32 + kcol));
  }
  #pragma unroll
  for (int nt = 0; nt < 2; ++nt)
    #pragma unroll
    for (int kc = 0; kc < 2; ++kc) { KEEP(w1pf[nt][kc]); KEEP(w00f[nt][kc]); }
  #pragma unroll
  for (int kc = 0; kc < 8; ++kc) KEEP(wc[kc]);
  #pragma unroll
  for (int kc = 0; kc < 12; ++kc) KEEP(wa[kc]);
  if (w < 4) {
    #pragma unroll
    for (int kc = 0; kc < 4; ++kc) KEEP(wo[kc]);
  }

  // hoisted biases
  float bias1p[2], bias00[2];
  #pragma unroll
  for (int nt = 0; nt < 2; ++nt) {
    int n = w * 32 + nt * 16 + ln;
    bias1p[nt] = b1p[e1 * 256 + n];
    bias00[nt] = b00[e0 * 256 + n];
  }
  float bias01 = b01[e0 * 128 + w * 16 + ln];
  float bias1a = b1a[e1 * 128 + w * 16 + ln];
  float bias1o = (w < 4) ? b1o[e1 * 32 + (w >> 1) * 16 + ln] : 0.f;

  const f32x4 z4 = {0.f, 0.f, 0.f, 0.f};

  // ---- gather helper (manually inlined below via macro) ----
#define GATHER(ROWA, AX)                                                       \
  {                                                                            \
    _Pragma("unroll")                                                          \
    for (int mt = 0; mt < 2; ++mt) {                                           \
      _Pragma("unroll")                                                        \
      for (int half = 0; half < 2; ++half) {                                   \
        _Pragma("unroll")                                                      \
        for (int kc = 0; kc < 2; ++kc) {                                       \
          bf16x8 a;                                                            \
          int rg = (ROWA)[mt];                                                 \
          if (rg >= 0) {                                                       \
            const float* q = inp + (size_t)rg * 144 + half * 64 + kc * 32 + kcol; \
            float4 u = *(const float4*)(q);                                    \
            float4 v = *(const float4*)(q + 4);                                \
            a[0] = (__bf16)u.x; a[1] = (__bf16)u.y; a[2] = (__bf16)u.z; a[3] = (__bf16)u.w; \
            a[4] = (__bf16)v.x; a[5] = (__bf16)v.y; a[6] = (__bf16)v.z; a[7] = (__bf16)v.w; \
          } else {                                                             \
            _Pragma("unroll")                                                  \
            for (int j = 0; j < 8; ++j) a[j] = (__bf16)0.f;                    \
          }                                                                    \
          (AX)[half][mt][kc] = a;                                              \
        }                                                                      \
      }                                                                        \
    }                                                                          \
  }

  // prologue: rowA + inputs for first tile
  int rowA[2];
  {
    int t = slice;
    int nr0 = min(32, cnt - t * 32);
    const int* rl = rlbase + t * 32;
    #pragma unroll
    for (int mt = 0; mt < 2; ++mt) {
      int rloc = mt * 16 + ln;
      rowA[mt] = (rloc < nr0) ? rl[rloc] : -1;
    }
  }
  bf16x8 axf[2][2][2];
  GATHER(rowA, axf);

  for (int t = slice; t < ntiles; t += 4) {
    int nr = min(32, cnt - t * 32);
    const int* rl = rlbase + t * 32;

    // prefetch next tile's row indices early (independent)
    int rowN[2] = {-1, -1};
    int t2 = t + 4;
    if (t2 < ntiles) {
      int nr2 = min(32, cnt - t2 * 32);
      const int* rl2 = rlbase + t2 * 32;
      #pragma unroll
      for (int mt = 0; mt < 2; ++mt) {
        int rloc = mt * 16 + ln;
        rowN[mt] = (rloc < nr2) ? rl2[rloc] : -1;
      }
    }

    // ===== P1: L1p -> G, L00 -> H1 =====
    #pragma unroll
    for (int nt = 0; nt < 2; ++nt) {
      int n = w * 32 + nt * 16 + ln;
      f32x4 acc[2] = {z4, z4};
      #pragma unroll
      for (int kc = 0; kc < 2; ++kc)
        #pragma unroll
        for (int mt = 0; mt < 2; ++mt)
          acc[mt] = __builtin_amdgcn_mfma_f32_16x16x32_bf16(axf[1][mt][kc], w1pf[nt][kc], acc[mt], 0, 0, 0);
      #pragma unroll
      for (int mt = 0; mt < 2; ++mt)
        #pragma unroll
        for (int r = 0; r < 4; ++r) {
          int row = mt * 16 + lq * 4 + r;
          float v = fmaxf(acc[mt][r] + bias1p[nt], 0.f);
          G[(row * 512 + ((n << 1) ^ ((row & 7) << 4))) >> 1] = f2bf(v);
        }
    }
    #pragma unroll
    for (int nt = 0; nt < 2; ++nt) {
      int n = w * 32 + nt * 16 + ln;
      f32x4 acc[2] = {z4, z4};
      #pragma unroll
      for (int kc = 0; kc < 2; ++kc)
        #pragma unroll
        for (int mt = 0; mt < 2; ++mt)
          acc[mt] = __builtin_amdgcn_mfma_f32_16x16x32_bf16(axf[0][mt][kc], w00f[nt][kc], acc[mt], 0, 0, 0);
      #pragma unroll
      for (int mt = 0; mt < 2; ++mt)
        #pragma unroll
        for (int r = 0; r < 4; ++r) {
          int row = mt * 16 + lq * 4 + r;
          float v = fmaxf(acc[mt][r] + bias00[nt], 0.f);
          H1m[(row * 512 + ((n << 1) ^ ((row & 7) << 4))) >> 1] = f2bf(v);
        }
    }

    // prefetch next tile's input fragments; pin so the loads issue here,
    // overlapping the barrier + P2/P3 latency.
    bf16x8 axn[2][2][2];
    GATHER(rowN, axn);
    #pragma unroll
    for (int half = 0; half < 2; ++half)
      #pragma unroll
      for (int mt = 0; mt < 2; ++mt)
        #pragma unroll
        for (int kc = 0; kc < 2; ++kc) KEEP(axn[half][mt][kc]);

    __syncthreads();  // bar1: G, H1 visible

    // ===== P2: L01: H1 @ wc -> HO =====
    {
      f32x4 accc[2] = {z4, z4};
      #pragma unroll
      for (int kc = 0; kc < 8; ++kc) {
        bf16x8 afr[2];
        #pragma unroll
        for (int mt = 0; mt < 2; ++mt) {
          int row = mt * 16 + ln;
          afr[mt] = *(const bf16x8*)&H1m[(row * 512 + (((kc * 32 + kcol) << 1) ^ ((row & 7) << 4))) >> 1];
        }
        #pragma unroll
        for (int mt = 0; mt < 2; ++mt)
          accc[mt] = __builtin_amdgcn_mfma_f32_16x16x32_bf16(afr[mt], wc[kc], accc[mt], 0, 0, 0);
      }
      int n = w * 16 + ln;
      #pragma unroll
      for (int mt = 0; mt < 2; ++mt)
        #pragma unroll
        for (int r = 0; r < 4; ++r) {
          int row = mt * 16 + lq * 4 + r;
          float v = fmaxf(accc[mt][r] + bias01, 0.f);
          HO[(row * 256 + ((n << 1) ^ ((row & 7) << 4))) >> 1] = f2bf(v);
        }
    }
    __syncthreads();  // bar2: HO visible

    // ===== P3: L1a: [HO | G] @ wa -> G2 =====
    {
      f32x4 acc1a[2] = {z4, z4};
      #pragma unroll
      for (int kc = 0; kc < 4; ++kc) {
        bf16x8 afr[2];
        #pragma unroll
        for (int mt = 0; mt < 2; ++mt) {
          int row = mt * 16 + ln;
          afr[mt] = *(const bf16x8*)&HO[(row * 256 + (((kc * 32 + kcol) << 1) ^ ((row & 7) << 4))) >> 1];
        }
        #pragma unroll
        for (int mt = 0; mt < 2; ++mt)
          acc1a[mt] = __builtin_amdgcn_mfma_f32_16x16x32_bf16(afr[mt], wa[kc], acc1a[mt], 0, 0, 0);
      }
      #pragma unroll
      for (int kc = 4; kc < 12; ++kc) {
        int kk = kc - 4;
        bf16x8 afr[2];
        #pragma unroll
        for (int mt = 0; mt < 2; ++mt) {
          int row = mt * 16 + ln;
          afr[mt] = *(const bf16x8*)&G[(row * 512 + (((kk * 32 + kcol) << 1) ^ ((row & 7) << 4))) >> 1];
        }
        #pragma unroll
        for (int mt = 0; mt < 2; ++mt)
          acc1a[mt] = __builtin_amdgcn_mfma_f32_16x16x32_bf16(afr[mt], wa[kc], acc1a[mt], 0, 0, 0);
      }
      int n = w * 16 + ln;
      #pragma unroll
      for (int mt = 0; mt < 2; ++mt)
        #pragma unroll
        for (int r = 0; r < 4; ++r) {
          int row = mt * 16 + lq * 4 + r;
          float v = fmaxf(acc1a[mt][r] + bias1a, 0.f);
          G2[(row * 256 + ((n << 1) ^ ((row & 7) << 4))) >> 1] = f2bf(v);
        }
    }
    __syncthreads();  // bar3: G2 visible; all G/H1/HO reads done

    // ===== P4: L1o (waves 0..3): G2 @ wo -> out. Waves 4..7 fall through to
    //       next P1 (writes G/H1 only; G2 is private, synced again at bar1).
    if (w < 4) {
      int mt = w & 1;
      int n  = (w >> 1) * 16 + ln;
      f32x4 acc = z4;
      #pragma unroll
      for (int kc = 0; kc < 4; ++kc) {
        int row = mt * 16 + ln;
        bf16x8 afr = *(const bf16x8*)&G2[(row * 256 + (((kc * 32 + kcol) << 1) ^ ((row & 7) << 4))) >> 1];
        acc = __builtin_amdgcn_mfma_f32_16x16x32_bf16(afr, wo[kc], acc, 0, 0, 0);
      }
      #pragma unroll
      for (int r = 0; r < 4; ++r) {
        int row = mt * 16 + lq * 4 + r;
        if (row < nr) {
          int rg = rl[row];
          out[(size_t)rg * 32 + n] = acc[r] + bias1o;
        }
      }
    }

    // rotate prefetched inputs
    #pragma unroll
    for (int half = 0; half < 2; ++half)
      #pragma unroll
      for (int mt = 0; mt < 2; ++mt)
        #pragma unroll
        for (int kc = 0; kc < 2; ++kc) axf[half][mt][kc] = axn[half][mt][kc];
    rowA[0] = rowN[0]; rowA[1] = rowN[1];
  }
#undef GATHER
}

extern "C" void kernel_launch(void* const* d_in, const int* in_sizes, int n_in,
                              void* d_out, int out_size, void* d_ws, size_t ws_size,
                              hipStream_t stream) {
  const float* inp = (const float*)d_in[0];
  const float* w00 = (const float*)d_in[1];
  const float* b00 = (const float*)d_in[2];
  const float* w01 = (const float*)d_in[3];
  const float* b01 = (const float*)d_in[4];
  const float* w1p = (const float*)d_in[5];
  const float* b1p = (const float*)d_in[6];
  const float* w1a = (const float*)d_in[7];
  const float* b1a = (const float*)d_in[8];
  const float* w1o = (const float*)d_in[9];
  const float* b1o = (const float*)d_in[10];
  char*  ws  = (char*)d_ws;
  float* out = (float*)d_out;

  k_combo<<<368, 256, 0, stream>>>(w00, w01, w1p, w1a, w1o, inp, ws);
  k_scan<<<1, 1024, 0, stream>>>((const int*)(ws + WS_BH), (int*)(ws + WS_CNT),
                                 (int*)(ws + WS_BASE), (int*)(ws + WS_OFF));
  k_scatter<<<NBLK, 256, 0, stream>>>((const int*)(ws + WS_PAIR),
                                      (const int*)(ws + WS_OFF),
                                      (int*)(ws + WS_ROWLIST));
  k_fused<<<256, 512, 0, stream>>>(inp, b00, b01, b1p, b1a, b1o, ws, out);
}